// Round 14
// baseline (182.997 us; speedup 1.0000x reference)
//
#include <hip/hip_runtime.h>
#include <hip/hip_fp16.h>
#include <cstdint>
#include <cstddef>

#define NN 8192
#define ATOMF 64
#define HID 128
#define HEADS 8
#define NG 256
#define ELLW 192
#define NEGSLOPE 0.2f

typedef unsigned long long u64;

// ================= K1: adj -> ELL (R12 verbatim; tb.w = degree) ====
__global__ __launch_bounds__(256, 4) void k_scan_ell(const float* __restrict__ adj,
                                                     int* __restrict__ ell,
                                                     int4* __restrict__ tb) {
    __shared__ u64 bml[4][128];
    int t = threadIdx.x, wid = t >> 6, l = t & 63;
    int row = blockIdx.x * 4 + wid;
    const float4* a4 = (const float4*)(adj + (size_t)row * NN);
    u64* bmr = bml[wid];
    #pragma unroll 8
    for (int s = 0; s < 32; ++s) {
        float4 v = a4[s * 64 + l];                  // coalesced 1 KB per wave-instr
        u64 b0 = __ballot(v.x > 0.f);
        u64 b1 = __ballot(v.y > 0.f);
        u64 b2 = __ballot(v.z > 0.f);
        u64 b3 = __ballot(v.w > 0.f);
        if (l < 4) bmr[s * 4 + l] = (l == 0) ? b0 : (l == 1) ? b1 : (l == 2) ? b2 : b3;
    }
    __syncthreads();
    u64 w0 = bmr[2 * l];
    u64 w1 = bmr[2 * l + 1];
    int c = __popcll(w0) + __popcll(w1);
    int incl = c;
    #pragma unroll
    for (int o = 1; o < 64; o <<= 1) {
        int u = __shfl_up(incl, o);
        if (l >= o) incl += u;
    }
    int pos = incl - c;
    int total = __shfl(incl, 63);
    if (l == 0) {
        int4 b;
        b.x = b.y = b.z = 0;
        b.w = total < ELLW ? total : ELLW;
        tb[row] = b;
    }
    int* er = ell + (size_t)row * ELLW;
    int gw0 = 2 * l, gw1 = 2 * l + 1;
    int base0 = (gw0 >> 2) * 256 + (gw0 & 3);
    int base1 = (gw1 >> 2) * 256 + (gw1 & 3);
    while (w0) {
        int bit = __builtin_ctzll(w0);
        w0 &= w0 - 1;
        if (pos < ELLW) er[pos++] = base0 + 4 * bit;
    }
    while (w1) {
        int bit = __builtin_ctzll(w1);
        w1 &= w1 - 1;
        if (pos < ELLW) er[pos++] = base1 + 4 * bit;
    }
}

// ================= K2: wreduce + gemm0/scores0 — writes g0 as fp16 ====
__global__ __launch_bounds__(256) void k_front2(
    const float* __restrict__ x,
    const float* __restrict__ W0, const float* __restrict__ a0s, const float* __restrict__ a0d,
    const float* __restrict__ W1, const float* __restrict__ W2,
    float* __restrict__ Wr1, float* __restrict__ Wr2,
    __half* __restrict__ g016, float* __restrict__ ssrc, float* __restrict__ sdst) {
    int b = blockIdx.x, t = threadIdx.x;
    if (b < 128) {
        const float* W = (b < 64) ? W1 : W2;
        float* Wr = (b < 64) ? Wr1 : Wr2;
        int i = (b & 63) * 256 + t;
        int k = i >> 7, cc = i & 127;
        float s = 0.f;
        #pragma unroll
        for (int h = 0; h < HEADS; ++h) s += W[(size_t)(h * HID + k) * HID + cc];
        Wr[i] = s;
    } else {
        __shared__ float Xl[32 * ATOMF];
        int row0 = (b - 128) * 32;
        const float4* Xg = (const float4*)(x + (size_t)row0 * ATOMF);
        float4* Xl4 = (float4*)Xl;
        #pragma unroll
        for (int i = t; i < 32 * ATOMF / 4; i += 256) Xl4[i] = Xg[i];
        __syncthreads();
        int cg = t & 31, rg = t >> 5;
        int c0 = cg * 4;
        float acc[4][4];
        #pragma unroll
        for (int r = 0; r < 4; ++r)
            #pragma unroll
            for (int c = 0; c < 4; ++c) acc[r][c] = 0.f;
        for (int k = 0; k < ATOMF; k += 4) {
            float4 w0 = *(const float4*)(W0 + (size_t)(k + 0) * HID + c0);
            float4 w1 = *(const float4*)(W0 + (size_t)(k + 1) * HID + c0);
            float4 w2 = *(const float4*)(W0 + (size_t)(k + 2) * HID + c0);
            float4 w3 = *(const float4*)(W0 + (size_t)(k + 3) * HID + c0);
            #pragma unroll
            for (int r = 0; r < 4; ++r) {
                float4 xv = *(const float4*)(&Xl[(rg * 4 + r) * ATOMF + k]);
                acc[r][0] += xv.x * w0.x + xv.y * w1.x + xv.z * w2.x + xv.w * w3.x;
                acc[r][1] += xv.x * w0.y + xv.y * w1.y + xv.z * w2.y + xv.w * w3.y;
                acc[r][2] += xv.x * w0.z + xv.y * w1.z + xv.z * w2.z + xv.w * w3.z;
                acc[r][3] += xv.x * w0.w + xv.y * w1.w + xv.z * w2.w + xv.w * w3.w;
            }
        }
        float4 asv = *(const float4*)(a0s + c0);
        float4 adv = *(const float4*)(a0d + c0);
        #pragma unroll
        for (int r = 0; r < 4; ++r) {
            int row = row0 + rg * 4 + r;
            __half2 p0 = __floats2half2_rn(acc[r][0], acc[r][1]);
            __half2 p1 = __floats2half2_rn(acc[r][2], acc[r][3]);
            __half2* gp = (__half2*)(g016 + (size_t)row * HID + c0);
            gp[0] = p0; gp[1] = p1;
            float ps = acc[r][0] * asv.x + acc[r][1] * asv.y + acc[r][2] * asv.z + acc[r][3] * asv.w;
            float pd = acc[r][0] * adv.x + acc[r][1] * adv.y + acc[r][2] * adv.z + acc[r][3] * adv.w;
            #pragma unroll
            for (int o = 16; o; o >>= 1) {
                ps += __shfl_xor(ps, o);
                pd += __shfl_xor(pd, o);
            }
            if (cg == 0) { ssrc[row] = ps; sdst[row] = pd; }
        }
    }
}

// ================= K3/K4/K5: fused layer — fp16 gather, single-pass softmax =====
// R10 structure (1 wave/row, 4 rows/block, no barriers). Gather reads 256 B/row
// (half the bytes); scores/denominator/gemm all stay f32.
template<int DO_GEMM>
__global__ __launch_bounds__(256, 4) void k_layer(
    const __half* __restrict__ h16, const float* __restrict__ ssrc_in,
    const float* __restrict__ sdst_in,
    const int* __restrict__ ell, const int4* __restrict__ tb,
    const float* __restrict__ Wr, const float* __restrict__ as_,
    const float* __restrict__ ad_,
    __half* __restrict__ gout16, float* __restrict__ gout32,
    float* __restrict__ ssrc_out, float* __restrict__ sdst_out) {
    __shared__ float wls[4][ELLW + 2];
    __shared__ int   jls[4][ELLW + 2];
    __shared__ float xls[4][HID];
    int wid = threadIdx.x >> 6, l = threadIdx.x & 63;
    int row = blockIdx.x * 4 + wid;
    float* wl = wls[wid];
    int* jl = jls[wid];
    int d = tb[row].w;
    float si = ssrc_in[row];
    const int* er = ell + (size_t)row * ELLW;
    // phase A (single pass, R13-validated): w = exp(leakyrelu(si+sj)), denom
    float s = 0.f;
    for (int k = l; k < d; k += 64) {
        int j = er[k];
        float e = si + sdst_in[j];
        e = e > 0.f ? e : NEGSLOPE * e;
        float w = __expf(e);
        jl[k] = j << 7;                              // j * HID (halves)
        wl[k] = w;
        s += w;
    }
    #pragma unroll
    for (int o = 32; o; o >>= 1) s += __shfl_xor(s, o);
    float inv = 1.f / s;
    if ((d & 1) && l == 0) { wl[d] = 0.f; jl[d] = 0; }   // pad to even (wave-private)
    int dpad = d + (d & 1);
    // phase C: 2 edges per step; lane reads 8 B (4 halves) of its dims
    int half = l >> 5;
    int d0 = (l & 31) * 4;
    const __half* hd = h16 + d0;
    float4 acc = make_float4(0.f, 0.f, 0.f, 0.f);
    int k = 0;
    for (; k + 8 <= dpad; k += 8) {
        int j0 = jl[k + half],     j1 = jl[k + 2 + half];
        int j2 = jl[k + 4 + half], j3 = jl[k + 6 + half];
        float w0 = wl[k + half],     w1 = wl[k + 2 + half];
        float w2 = wl[k + 4 + half], w3 = wl[k + 6 + half];
        int2 r0 = *(const int2*)(hd + j0);
        int2 r1 = *(const int2*)(hd + j1);
        int2 r2 = *(const int2*)(hd + j2);
        int2 r3 = *(const int2*)(hd + j3);
        float2 a0 = __half22float2(*(__half2*)&r0.x), b0 = __half22float2(*(__half2*)&r0.y);
        float2 a1 = __half22float2(*(__half2*)&r1.x), b1 = __half22float2(*(__half2*)&r1.y);
        float2 a2 = __half22float2(*(__half2*)&r2.x), b2 = __half22float2(*(__half2*)&r2.y);
        float2 a3 = __half22float2(*(__half2*)&r3.x), b3 = __half22float2(*(__half2*)&r3.y);
        acc.x += w0 * a0.x; acc.y += w0 * a0.y; acc.z += w0 * b0.x; acc.w += w0 * b0.y;
        acc.x += w1 * a1.x; acc.y += w1 * a1.y; acc.z += w1 * b1.x; acc.w += w1 * b1.y;
        acc.x += w2 * a2.x; acc.y += w2 * a2.y; acc.z += w2 * b2.x; acc.w += w2 * b2.y;
        acc.x += w3 * a3.x; acc.y += w3 * a3.y; acc.z += w3 * b3.x; acc.w += w3 * b3.y;
    }
    for (; k < dpad; k += 2) {
        int j = jl[k + half];
        float w = wl[k + half];
        int2 r0 = *(const int2*)(hd + j);
        float2 a0 = __half22float2(*(__half2*)&r0.x), b0 = __half22float2(*(__half2*)&r0.y);
        acc.x += w * a0.x; acc.y += w * a0.y; acc.z += w * b0.x; acc.w += w * b0.y;
    }
    acc.x += __shfl_xor(acc.x, 32);
    acc.y += __shfl_xor(acc.y, 32);
    acc.z += __shfl_xor(acc.z, 32);
    acc.w += __shfl_xor(acc.w, 32);
    acc.x *= inv; acc.y *= inv; acc.z *= inv; acc.w *= inv;
    if (DO_GEMM == 0) {
        if (l < 32)
            *(float4*)(gout32 + (size_t)row * HID + d0) = acc;
        return;
    }
    // stage relu(o_row) f32 into wave-private LDS (lanes 0-31 cover 128 dims)
    float* xl = xls[wid];
    if (l < 32) {
        float4 r;
        r.x = fmaxf(acc.x, 0.f); r.y = fmaxf(acc.y, 0.f);
        r.z = fmaxf(acc.z, 0.f); r.w = fmaxf(acc.w, 0.f);
        *(float4*)(xl + d0) = r;
    }
    // wave-private gemm: lane owns ADJACENT cols 2l, 2l+1 (fp16-packable)
    int c2 = 2 * l;
    float acc0 = 0.f, acc1 = 0.f;
    for (int kk = 0; kk < HID; kk += 4) {
        float4 xv = *(const float4*)(&xl[kk]);      // uniform addr: LDS broadcast
        float2 w0 = *(const float2*)(Wr + (size_t)(kk + 0) * HID + c2);
        float2 w1 = *(const float2*)(Wr + (size_t)(kk + 1) * HID + c2);
        float2 w2 = *(const float2*)(Wr + (size_t)(kk + 2) * HID + c2);
        float2 w3 = *(const float2*)(Wr + (size_t)(kk + 3) * HID + c2);
        acc0 += xv.x * w0.x + xv.y * w1.x + xv.z * w2.x + xv.w * w3.x;
        acc1 += xv.x * w0.y + xv.y * w1.y + xv.z * w2.y + xv.w * w3.y;
    }
    *(__half2*)(gout16 + (size_t)row * HID + c2) = __floats2half2_rn(acc0, acc1);
    float2 asv = *(const float2*)(as_ + c2);
    float2 adv = *(const float2*)(ad_ + c2);
    float ps = acc0 * asv.x + acc1 * asv.y;
    float pd = acc0 * adv.x + acc1 * adv.y;
    #pragma unroll
    for (int o = 32; o; o >>= 1) {
        ps += __shfl_xor(ps, o);
        pd += __shfl_xor(pd, o);
    }
    if (l == 0) { ssrc_out[row] = ps; sdst_out[row] = pd; }
}

// ================= K6: pool + fc (verbatim) =================
__global__ __launch_bounds__(256) void k_poolfc(const float* __restrict__ h,
                                                const int* __restrict__ batch,
                                                const float* __restrict__ fcw,
                                                const float* __restrict__ fcb,
                                                float* __restrict__ out) {
    int wid = threadIdx.x >> 6, l = threadIdx.x & 63;
    int g = blockIdx.x * 4 + wid;
    int lo = 0, hi = NN;
    while (lo < hi) { int mid = (lo + hi) >> 1; if (batch[mid] < g) lo = mid + 1; else hi = mid; }
    int e0 = lo;
    hi = NN;
    while (lo < hi) { int mid = (lo + hi) >> 1; if (batch[mid] <= g) lo = mid + 1; else hi = mid; }
    int e1 = lo;
    float sum = 0.f;
    for (int r = e0; r < e1; ++r) {
        const float* hr = h + (size_t)r * HID;
        sum += hr[l] * fcw[l] + hr[l + 64] * fcw[l + 64];
    }
    #pragma unroll
    for (int o = 32; o; o >>= 1) sum += __shfl_xor(sum, o);
    if (l == 0) out[g] = sum / fmaxf((float)(e1 - e0), 1.f) + fcb[0];
}

extern "C" void kernel_launch(void* const* d_in, const int* in_sizes, int n_in,
                              void* d_out, int out_size, void* d_ws, size_t ws_size,
                              hipStream_t stream) {
    const float* x    = (const float*)d_in[0];
    const float* adj  = (const float*)d_in[1];
    const int*   batch= (const int*)  d_in[2];
    const float* W0   = (const float*)d_in[3];
    const float* a0s  = (const float*)d_in[4];
    const float* a0d  = (const float*)d_in[5];
    const float* W1   = (const float*)d_in[6];
    const float* a1s  = (const float*)d_in[7];
    const float* a1d  = (const float*)d_in[8];
    const float* W2   = (const float*)d_in[9];
    const float* a2s  = (const float*)d_in[10];
    const float* a2d  = (const float*)d_in[11];
    const float* fcw  = (const float*)d_in[12];
    const float* fcb  = (const float*)d_in[13];
    float* out = (float*)d_out;

    char* ws = (char*)d_ws;
    size_t off = 0;
    auto alloc = [&](size_t bytes) {
        char* p = ws + off;
        off = (off + bytes + 255) & ~255UL;
        return p;
    };
    int*    ell  = (int*)   alloc((size_t)NN * ELLW * 4);   // 6.3 MB
    int4*   tb   = (int4*)  alloc((size_t)NN * 16);
    __half* hA16 = (__half*)alloc((size_t)NN * HID * 2);    // 2 MB
    __half* hB16 = (__half*)alloc((size_t)NN * HID * 2);    // 2 MB
    float*  h2   = (float*) alloc((size_t)NN * HID * 4);    // final f32
    float*  sAs  = (float*) alloc((size_t)NN * 4);
    float*  sAd  = (float*) alloc((size_t)NN * 4);
    float*  sBs  = (float*) alloc((size_t)NN * 4);
    float*  sBd  = (float*) alloc((size_t)NN * 4);
    float*  Wr1  = (float*) alloc((size_t)HID * HID * 4);
    float*  Wr2  = (float*) alloc((size_t)HID * HID * 4);
    (void)ws_size; (void)in_sizes; (void)n_in; (void)out_size;

    // K1: adj -> ELL (+ degree)
    k_scan_ell<<<NN / 4, 256, 0, stream>>>(adj, ell, tb);
    // K2: wreduce + gemm0/scores0 (g0 stored fp16)
    k_front2<<<128 + 256, 256, 0, stream>>>(x, W0, a0s, a0d, W1, W2,
                                            Wr1, Wr2, hA16, sAs, sAd);
    // K3: agg0 -> relu -> @Wr1 -> g1(fp16) + scores1
    k_layer<1><<<NN / 4, 256, 0, stream>>>(hA16, sAs, sAd, ell, tb, Wr1, a1s, a1d,
                                           hB16, nullptr, sBs, sBd);
    // K4: agg1 -> relu -> @Wr2 -> g2(fp16) + scores2
    k_layer<1><<<NN / 4, 256, 0, stream>>>(hB16, sBs, sBd, ell, tb, Wr2, a2s, a2d,
                                           hA16, nullptr, sAs, sAd);
    // K5: agg2 -> h2 (f32)
    k_layer<0><<<NN / 4, 256, 0, stream>>>(hA16, sAs, sAd, ell, tb, nullptr, nullptr,
                                           nullptr, nullptr, h2, nullptr, nullptr);
    // K6: pool + fc
    k_poolfc<<<NG / 4, 256, 0, stream>>>(h2, batch, fcw, fcb, out);
}

// Round 15
// 173.216 us; speedup vs baseline: 1.0565x; 1.0565x over previous
//
#include <hip/hip_runtime.h>
#include <hip/hip_fp16.h>
#include <cstdint>
#include <cstddef>

#define NN 8192
#define ATOMF 64
#define HID 128
#define HEADS 8
#define NG 256
#define ELLW 192
#define NEGSLOPE 0.2f

typedef unsigned long long u64;

// ================= K1: adj -> ELL (verbatim; tb.w = degree) ====
__global__ __launch_bounds__(256, 4) void k_scan_ell(const float* __restrict__ adj,
                                                     int* __restrict__ ell,
                                                     int4* __restrict__ tb) {
    __shared__ u64 bml[4][128];
    int t = threadIdx.x, wid = t >> 6, l = t & 63;
    int row = blockIdx.x * 4 + wid;
    const float4* a4 = (const float4*)(adj + (size_t)row * NN);
    u64* bmr = bml[wid];
    #pragma unroll 8
    for (int s = 0; s < 32; ++s) {
        float4 v = a4[s * 64 + l];                  // coalesced 1 KB per wave-instr
        u64 b0 = __ballot(v.x > 0.f);
        u64 b1 = __ballot(v.y > 0.f);
        u64 b2 = __ballot(v.z > 0.f);
        u64 b3 = __ballot(v.w > 0.f);
        if (l < 4) bmr[s * 4 + l] = (l == 0) ? b0 : (l == 1) ? b1 : (l == 2) ? b2 : b3;
    }
    __syncthreads();
    u64 w0 = bmr[2 * l];
    u64 w1 = bmr[2 * l + 1];
    int c = __popcll(w0) + __popcll(w1);
    int incl = c;
    #pragma unroll
    for (int o = 1; o < 64; o <<= 1) {
        int u = __shfl_up(incl, o);
        if (l >= o) incl += u;
    }
    int pos = incl - c;
    int total = __shfl(incl, 63);
    if (l == 0) {
        int4 b;
        b.x = b.y = b.z = 0;
        b.w = total < ELLW ? total : ELLW;
        tb[row] = b;
    }
    int* er = ell + (size_t)row * ELLW;
    int gw0 = 2 * l, gw1 = 2 * l + 1;
    int base0 = (gw0 >> 2) * 256 + (gw0 & 3);
    int base1 = (gw1 >> 2) * 256 + (gw1 & 3);
    while (w0) {
        int bit = __builtin_ctzll(w0);
        w0 &= w0 - 1;
        if (pos < ELLW) er[pos++] = base0 + 4 * bit;
    }
    while (w1) {
        int bit = __builtin_ctzll(w1);
        w1 &= w1 - 1;
        if (pos < ELLW) er[pos++] = base1 + 4 * bit;
    }
}

// ================= K2: wreduce + gemm0/scores0 — writes g0 as fp16 (verbatim) ====
__global__ __launch_bounds__(256) void k_front2(
    const float* __restrict__ x,
    const float* __restrict__ W0, const float* __restrict__ a0s, const float* __restrict__ a0d,
    const float* __restrict__ W1, const float* __restrict__ W2,
    float* __restrict__ Wr1, float* __restrict__ Wr2,
    __half* __restrict__ g016, float* __restrict__ ssrc, float* __restrict__ sdst) {
    int b = blockIdx.x, t = threadIdx.x;
    if (b < 128) {
        const float* W = (b < 64) ? W1 : W2;
        float* Wr = (b < 64) ? Wr1 : Wr2;
        int i = (b & 63) * 256 + t;
        int k = i >> 7, cc = i & 127;
        float s = 0.f;
        #pragma unroll
        for (int h = 0; h < HEADS; ++h) s += W[(size_t)(h * HID + k) * HID + cc];
        Wr[i] = s;
    } else {
        __shared__ float Xl[32 * ATOMF];
        int row0 = (b - 128) * 32;
        const float4* Xg = (const float4*)(x + (size_t)row0 * ATOMF);
        float4* Xl4 = (float4*)Xl;
        #pragma unroll
        for (int i = t; i < 32 * ATOMF / 4; i += 256) Xl4[i] = Xg[i];
        __syncthreads();
        int cg = t & 31, rg = t >> 5;
        int c0 = cg * 4;
        float acc[4][4];
        #pragma unroll
        for (int r = 0; r < 4; ++r)
            #pragma unroll
            for (int c = 0; c < 4; ++c) acc[r][c] = 0.f;
        for (int k = 0; k < ATOMF; k += 4) {
            float4 w0 = *(const float4*)(W0 + (size_t)(k + 0) * HID + c0);
            float4 w1 = *(const float4*)(W0 + (size_t)(k + 1) * HID + c0);
            float4 w2 = *(const float4*)(W0 + (size_t)(k + 2) * HID + c0);
            float4 w3 = *(const float4*)(W0 + (size_t)(k + 3) * HID + c0);
            #pragma unroll
            for (int r = 0; r < 4; ++r) {
                float4 xv = *(const float4*)(&Xl[(rg * 4 + r) * ATOMF + k]);
                acc[r][0] += xv.x * w0.x + xv.y * w1.x + xv.z * w2.x + xv.w * w3.x;
                acc[r][1] += xv.x * w0.y + xv.y * w1.y + xv.z * w2.y + xv.w * w3.y;
                acc[r][2] += xv.x * w0.z + xv.y * w1.z + xv.z * w2.z + xv.w * w3.z;
                acc[r][3] += xv.x * w0.w + xv.y * w1.w + xv.z * w2.w + xv.w * w3.w;
            }
        }
        float4 asv = *(const float4*)(a0s + c0);
        float4 adv = *(const float4*)(a0d + c0);
        #pragma unroll
        for (int r = 0; r < 4; ++r) {
            int row = row0 + rg * 4 + r;
            __half2 p0 = __floats2half2_rn(acc[r][0], acc[r][1]);
            __half2 p1 = __floats2half2_rn(acc[r][2], acc[r][3]);
            __half2* gp = (__half2*)(g016 + (size_t)row * HID + c0);
            gp[0] = p0; gp[1] = p1;
            float ps = acc[r][0] * asv.x + acc[r][1] * asv.y + acc[r][2] * asv.z + acc[r][3] * asv.w;
            float pd = acc[r][0] * adv.x + acc[r][1] * adv.y + acc[r][2] * adv.z + acc[r][3] * adv.w;
            #pragma unroll
            for (int o = 16; o; o >>= 1) {
                ps += __shfl_xor(ps, o);
                pd += __shfl_xor(pd, o);
            }
            if (cg == 0) { ssrc[row] = ps; sdst[row] = pd; }
        }
    }
}

// ================= K3/K4/K5: fused layer — 4 edges per VMEM instruction =====
// fp16 h; lane l: quarter q=l>>4 takes edge slot k+q, dims (l&15)*8..+7 (16 B).
// One dwordx4 instruction covers 4 edges. Post-loop shfl_xor(16,32) combines
// quarters; lanes 0-15 hold the final row. Single-pass softmax (R13-validated).
template<int DO_GEMM>
__global__ __launch_bounds__(256, 4) void k_layer(
    const __half* __restrict__ h16, const float* __restrict__ ssrc_in,
    const float* __restrict__ sdst_in,
    const int* __restrict__ ell, const int4* __restrict__ tb,
    const float* __restrict__ Wr, const float* __restrict__ as_,
    const float* __restrict__ ad_,
    __half* __restrict__ gout16, float* __restrict__ gout32,
    float* __restrict__ ssrc_out, float* __restrict__ sdst_out) {
    __shared__ float wls[4][ELLW + 4];
    __shared__ int   jls[4][ELLW + 4];
    __shared__ float xls[4][HID];
    int wid = threadIdx.x >> 6, l = threadIdx.x & 63;
    int row = blockIdx.x * 4 + wid;
    float* wl = wls[wid];
    int* jl = jls[wid];
    int d = tb[row].w;
    float si = ssrc_in[row];
    const int* er = ell + (size_t)row * ELLW;
    // phase A (single pass): w = exp(leakyrelu(si+sj)), denom
    float s = 0.f;
    for (int k = l; k < d; k += 64) {
        int j = er[k];
        float e = si + sdst_in[j];
        e = e > 0.f ? e : NEGSLOPE * e;
        float w = __expf(e);
        jl[k] = j << 7;                              // j * HID (halves)
        wl[k] = w;
        s += w;
    }
    #pragma unroll
    for (int o = 32; o; o >>= 1) s += __shfl_xor(s, o);
    float inv = 1.f / s;
    int dpad = (d + 3) & ~3;
    if (l < 3 && d + l < dpad) { wl[d + l] = 0.f; jl[d + l] = 0; }  // pad to mult of 4
    int q = l >> 4;
    int d0 = (l & 15) * 8;
    const __half* hd = h16 + d0;
    float a0 = 0.f, a1 = 0.f, a2 = 0.f, a3 = 0.f;
    float a4 = 0.f, a5 = 0.f, a6 = 0.f, a7 = 0.f;
    int k = 0;
    for (; k + 8 <= dpad; k += 8) {                  // 2 quad-steps: 2 loads in flight
        int jA = jl[k + q], jB = jl[k + 4 + q];
        float wA = wl[k + q], wB = wl[k + 4 + q];
        int4 rA = *(const int4*)(hd + jA);
        int4 rB = *(const int4*)(hd + jB);
        float2 fA0 = __half22float2(*(__half2*)&rA.x);
        float2 fA1 = __half22float2(*(((__half2*)&rA.x) + 1));
        float2 fA2 = __half22float2(*(__half2*)&rA.z);
        float2 fA3 = __half22float2(*(((__half2*)&rA.z) + 1));
        a0 += wA * fA0.x; a1 += wA * fA0.y; a2 += wA * fA1.x; a3 += wA * fA1.y;
        a4 += wA * fA2.x; a5 += wA * fA2.y; a6 += wA * fA3.x; a7 += wA * fA3.y;
        float2 fB0 = __half22float2(*(__half2*)&rB.x);
        float2 fB1 = __half22float2(*(((__half2*)&rB.x) + 1));
        float2 fB2 = __half22float2(*(__half2*)&rB.z);
        float2 fB3 = __half22float2(*(((__half2*)&rB.z) + 1));
        a0 += wB * fB0.x; a1 += wB * fB0.y; a2 += wB * fB1.x; a3 += wB * fB1.y;
        a4 += wB * fB2.x; a5 += wB * fB2.y; a6 += wB * fB3.x; a7 += wB * fB3.y;
    }
    for (; k < dpad; k += 4) {
        int jA = jl[k + q];
        float wA = wl[k + q];
        int4 rA = *(const int4*)(hd + jA);
        float2 fA0 = __half22float2(*(__half2*)&rA.x);
        float2 fA1 = __half22float2(*(((__half2*)&rA.x) + 1));
        float2 fA2 = __half22float2(*(__half2*)&rA.z);
        float2 fA3 = __half22float2(*(((__half2*)&rA.z) + 1));
        a0 += wA * fA0.x; a1 += wA * fA0.y; a2 += wA * fA1.x; a3 += wA * fA1.y;
        a4 += wA * fA2.x; a5 += wA * fA2.y; a6 += wA * fA3.x; a7 += wA * fA3.y;
    }
    // combine quarters: lanes l, l+16, l+32, l+48 hold same dim slice
    #pragma unroll
    for (int o = 16; o <= 32; o <<= 1) {
        a0 += __shfl_xor(a0, o); a1 += __shfl_xor(a1, o);
        a2 += __shfl_xor(a2, o); a3 += __shfl_xor(a3, o);
        a4 += __shfl_xor(a4, o); a5 += __shfl_xor(a5, o);
        a6 += __shfl_xor(a6, o); a7 += __shfl_xor(a7, o);
    }
    a0 *= inv; a1 *= inv; a2 *= inv; a3 *= inv;
    a4 *= inv; a5 *= inv; a6 *= inv; a7 *= inv;
    if (DO_GEMM == 0) {
        if (l < 16) {
            float* op = gout32 + (size_t)row * HID + d0;
            *(float4*)op       = make_float4(a0, a1, a2, a3);
            *(float4*)(op + 4) = make_float4(a4, a5, a6, a7);
        }
        return;
    }
    // stage relu(o_row) f32 into wave-private LDS (lanes 0-15 cover 128 dims)
    float* xl = xls[wid];
    if (l < 16) {
        *(float4*)(xl + d0)     = make_float4(fmaxf(a0, 0.f), fmaxf(a1, 0.f),
                                              fmaxf(a2, 0.f), fmaxf(a3, 0.f));
        *(float4*)(xl + d0 + 4) = make_float4(fmaxf(a4, 0.f), fmaxf(a5, 0.f),
                                              fmaxf(a6, 0.f), fmaxf(a7, 0.f));
    }
    // wave-private gemm: lane owns ADJACENT cols 2l, 2l+1
    int c2 = 2 * l;
    float acc0 = 0.f, acc1 = 0.f;
    for (int kk = 0; kk < HID; kk += 4) {
        float4 xv = *(const float4*)(&xl[kk]);      // uniform addr: LDS broadcast
        float2 w0 = *(const float2*)(Wr + (size_t)(kk + 0) * HID + c2);
        float2 w1 = *(const float2*)(Wr + (size_t)(kk + 1) * HID + c2);
        float2 w2 = *(const float2*)(Wr + (size_t)(kk + 2) * HID + c2);
        float2 w3 = *(const float2*)(Wr + (size_t)(kk + 3) * HID + c2);
        acc0 += xv.x * w0.x + xv.y * w1.x + xv.z * w2.x + xv.w * w3.x;
        acc1 += xv.x * w0.y + xv.y * w1.y + xv.z * w2.y + xv.w * w3.y;
    }
    *(__half2*)(gout16 + (size_t)row * HID + c2) = __floats2half2_rn(acc0, acc1);
    float2 asv = *(const float2*)(as_ + c2);
    float2 adv = *(const float2*)(ad_ + c2);
    float ps = acc0 * asv.x + acc1 * asv.y;
    float pd = acc0 * adv.x + acc1 * adv.y;
    #pragma unroll
    for (int o = 32; o; o >>= 1) {
        ps += __shfl_xor(ps, o);
        pd += __shfl_xor(pd, o);
    }
    if (l == 0) { ssrc_out[row] = ps; sdst_out[row] = pd; }
}

// ================= K6: pool + fc (verbatim) =================
__global__ __launch_bounds__(256) void k_poolfc(const float* __restrict__ h,
                                                const int* __restrict__ batch,
                                                const float* __restrict__ fcw,
                                                const float* __restrict__ fcb,
                                                float* __restrict__ out) {
    int wid = threadIdx.x >> 6, l = threadIdx.x & 63;
    int g = blockIdx.x * 4 + wid;
    int lo = 0, hi = NN;
    while (lo < hi) { int mid = (lo + hi) >> 1; if (batch[mid] < g) lo = mid + 1; else hi = mid; }
    int e0 = lo;
    hi = NN;
    while (lo < hi) { int mid = (lo + hi) >> 1; if (batch[mid] <= g) lo = mid + 1; else hi = mid; }
    int e1 = lo;
    float sum = 0.f;
    for (int r = e0; r < e1; ++r) {
        const float* hr = h + (size_t)r * HID;
        sum += hr[l] * fcw[l] + hr[l + 64] * fcw[l + 64];
    }
    #pragma unroll
    for (int o = 32; o; o >>= 1) sum += __shfl_xor(sum, o);
    if (l == 0) out[g] = sum / fmaxf((float)(e1 - e0), 1.f) + fcb[0];
}

extern "C" void kernel_launch(void* const* d_in, const int* in_sizes, int n_in,
                              void* d_out, int out_size, void* d_ws, size_t ws_size,
                              hipStream_t stream) {
    const float* x    = (const float*)d_in[0];
    const float* adj  = (const float*)d_in[1];
    const int*   batch= (const int*)  d_in[2];
    const float* W0   = (const float*)d_in[3];
    const float* a0s  = (const float*)d_in[4];
    const float* a0d  = (const float*)d_in[5];
    const float* W1   = (const float*)d_in[6];
    const float* a1s  = (const float*)d_in[7];
    const float* a1d  = (const float*)d_in[8];
    const float* W2   = (const float*)d_in[9];
    const float* a2s  = (const float*)d_in[10];
    const float* a2d  = (const float*)d_in[11];
    const float* fcw  = (const float*)d_in[12];
    const float* fcb  = (const float*)d_in[13];
    float* out = (float*)d_out;

    char* ws = (char*)d_ws;
    size_t off = 0;
    auto alloc = [&](size_t bytes) {
        char* p = ws + off;
        off = (off + bytes + 255) & ~255UL;
        return p;
    };
    int*    ell  = (int*)   alloc((size_t)NN * ELLW * 4);   // 6.3 MB
    int4*   tb   = (int4*)  alloc((size_t)NN * 16);
    __half* hA16 = (__half*)alloc((size_t)NN * HID * 2);    // 2 MB
    __half* hB16 = (__half*)alloc((size_t)NN * HID * 2);    // 2 MB
    float*  h2   = (float*) alloc((size_t)NN * HID * 4);    // final f32
    float*  sAs  = (float*) alloc((size_t)NN * 4);
    float*  sAd  = (float*) alloc((size_t)NN * 4);
    float*  sBs  = (float*) alloc((size_t)NN * 4);
    float*  sBd  = (float*) alloc((size_t)NN * 4);
    float*  Wr1  = (float*) alloc((size_t)HID * HID * 4);
    float*  Wr2  = (float*) alloc((size_t)HID * HID * 4);
    (void)ws_size; (void)in_sizes; (void)n_in; (void)out_size;

    // K1: adj -> ELL (+ degree)
    k_scan_ell<<<NN / 4, 256, 0, stream>>>(adj, ell, tb);
    // K2: wreduce + gemm0/scores0 (g0 stored fp16)
    k_front2<<<128 + 256, 256, 0, stream>>>(x, W0, a0s, a0d, W1, W2,
                                            Wr1, Wr2, hA16, sAs, sAd);
    // K3: agg0 -> relu -> @Wr1 -> g1(fp16) + scores1
    k_layer<1><<<NN / 4, 256, 0, stream>>>(hA16, sAs, sAd, ell, tb, Wr1, a1s, a1d,
                                           hB16, nullptr, sBs, sBd);
    // K4: agg1 -> relu -> @Wr2 -> g2(fp16) + scores2
    k_layer<1><<<NN / 4, 256, 0, stream>>>(hB16, sBs, sBd, ell, tb, Wr2, a2s, a2d,
                                           hA16, nullptr, sAs, sAd);
    // K5: agg2 -> h2 (f32)
    k_layer<0><<<NN / 4, 256, 0, stream>>>(hA16, sAs, sAd, ell, tb, nullptr, nullptr,
                                           nullptr, nullptr, h2, nullptr, nullptr);
    // K6: pool + fc
    k_poolfc<<<NG / 4, 256, 0, stream>>>(h2, batch, fcw, fcb, out);
}